// Round 1
// baseline (694.197 us; speedup 1.0000x reference)
//
#include <hip/hip_runtime.h>

#define NMEM 16384
#define MDIM 225
#define L1D 134
#define NPOS 17956   // 134*134
#define MCLS 4489    // 67*67
#define MPAD 4608    // 36*128
#define NCHUNK 8
#define CHUNK 2048

// ---------------------------------------------------------------------------
// K0: collapse each 15x15 mem filter to four parity-dependent 8x8 filters,
// and compute hn[n] = 0.5*||m_n||^2.
// cm layout: cm[class][k][n], k = u*8+v, class = er*2+ec.
// Row-collapse maps (er=0): i -> i>>1 ; (er=1): i -> (i+1)>>1.
// ---------------------------------------------------------------------------
__global__ __launch_bounds__(64) void prep_kernel(const float* __restrict__ mem,
                                                  float* __restrict__ cm,
                                                  float* __restrict__ hn) {
    __shared__ float lds[64 * 65];   // per-thread 65-float scratch (bank-conflict-free)
    const int t = threadIdx.x;
    const int n = blockIdx.x * 64 + t;
    float* row = lds + t * 65;
    const float* mrow = mem + n * MDIM;
    float nrm = 0.f;
    for (int c = 0; c < 4; ++c) {
        const int er = c >> 1, ec = c & 1;
        #pragma unroll
        for (int k = 0; k < 64; ++k) row[k] = 0.f;
        for (int i = 0; i < 15; ++i) {
            const int u = er ? ((i + 1) >> 1) : (i >> 1);
            for (int j = 0; j < 15; ++j) {
                const int v = ec ? ((j + 1) >> 1) : (j >> 1);
                const float val = mrow[i * 15 + j];
                row[u * 8 + v] += val;
                if (c == 0) nrm += val * val;
            }
        }
        float* cmc = cm + c * (64 * NMEM) + n;
        #pragma unroll
        for (int k = 0; k < 64; ++k) cmc[k * NMEM] = row[k];   // coalesced across threads
    }
    hn[n] = 0.5f * nrm;
}

// ---------------------------------------------------------------------------
// K1: GEMM X(4608x64) @ cm[class](64x16384) with fused running argmax of
// score = dot - hn[n]  (equiv. argmin of ||m||^2 - 2*dot).
// X[m][k]: m=(mr,mc) in 67x67, k=(u,v) in 8x8, value = img[mr-5+u][mc-5+v] (0 OOB).
// Grid: (mtile=36, nchunk=8, class=4). Block 256 threads, 128x128 tile, 8x8/thread.
// ---------------------------------------------------------------------------
__global__ __launch_bounds__(256) void gemm_argmin_kernel(const float* __restrict__ img,
                                                          const float* __restrict__ cm,
                                                          const float* __restrict__ hn,
                                                          float* __restrict__ pbest,
                                                          int* __restrict__ pidx) {
    __shared__ float xs[64 * 128];   // xs[k*128+m]
    __shared__ float cs[64 * 128];   // cs[k*128+n]
    const int mtile = blockIdx.x, nchunk = blockIdx.y, cls = blockIdx.z;
    const int t = threadIdx.x;
    const int tx = t & 15, ty = t >> 4;

    // Stage X tile (whole K=64 resident for the entire kernel).
    for (int e = t; e < 64 * 128; e += 256) {
        const int k = e >> 7, m = e & 127;
        const int mg = mtile * 128 + m;
        float v = 0.f;
        if (mg < MCLS) {
            const int mr = mg / 67, mc = mg - mr * 67;
            const int r = mr - 5 + (k >> 3), c2 = mc - 5 + (k & 7);
            if ((unsigned)r < 64u && (unsigned)c2 < 64u) v = img[r * 64 + c2];
        }
        xs[k * 128 + m] = v;
    }

    float best[8]; int bidx[8];
    #pragma unroll
    for (int i = 0; i < 8; ++i) { best[i] = -3.0e38f; bidx[i] = 0; }

    const float* cmc = cm + cls * (64 * NMEM) + nchunk * CHUNK;

    for (int nt = 0; nt < 16; ++nt) {
        __syncthreads();
        const float* src = cmc + nt * 128;
        for (int f = t; f < 2048; f += 256) {
            const int k = f >> 5, x4 = (f & 31) << 2;
            *(float4*)(cs + k * 128 + x4) = *(const float4*)(src + k * NMEM + x4);
        }
        __syncthreads();

        float acc[8][8];
        #pragma unroll
        for (int i = 0; i < 8; ++i)
            #pragma unroll
            for (int j = 0; j < 8; ++j) acc[i][j] = 0.f;

        for (int k = 0; k < 64; ++k) {
            const float4 a0 = *(const float4*)(xs + k * 128 + ty * 8);
            const float4 a1 = *(const float4*)(xs + k * 128 + ty * 8 + 4);
            const float4 b0 = *(const float4*)(cs + k * 128 + tx * 8);
            const float4 b1 = *(const float4*)(cs + k * 128 + tx * 8 + 4);
            const float a[8] = {a0.x, a0.y, a0.z, a0.w, a1.x, a1.y, a1.z, a1.w};
            const float b[8] = {b0.x, b0.y, b0.z, b0.w, b1.x, b1.y, b1.z, b1.w};
            #pragma unroll
            for (int i = 0; i < 8; ++i)
                #pragma unroll
                for (int j = 0; j < 8; ++j) acc[i][j] = fmaf(a[i], b[j], acc[i][j]);
        }

        const int nbase = nchunk * CHUNK + nt * 128 + tx * 8;
        const float4 h0 = *(const float4*)(hn + nbase);
        const float4 h1 = *(const float4*)(hn + nbase + 4);
        const float h[8] = {h0.x, h0.y, h0.z, h0.w, h1.x, h1.y, h1.z, h1.w};
        #pragma unroll
        for (int i = 0; i < 8; ++i) {
            #pragma unroll
            for (int j = 0; j < 8; ++j) {
                const float s = acc[i][j] - h[j];
                if (s > best[i]) { best[i] = s; bidx[i] = nbase + j; }
            }
        }
    }

    // Cross-thread argmax reduction per m-row (16 tx lanes share a row).
    __syncthreads();
    float* rs = xs;                   // reuse LDS: 128*16 floats
    int* ri = (int*)(xs + 2048);      // 128*16 ints
    #pragma unroll
    for (int i = 0; i < 8; ++i) {
        rs[(ty * 8 + i) * 16 + tx] = best[i];
        ri[(ty * 8 + i) * 16 + tx] = bidx[i];
    }
    __syncthreads();
    if (t < 128) {
        float b = rs[t * 16]; int bi = ri[t * 16];
        for (int x = 1; x < 16; ++x) {
            const float s = rs[t * 16 + x]; const int si = ri[t * 16 + x];
            if (s > b || (s == b && si < bi)) { b = s; bi = si; }
        }
        const int o = (cls * MPAD + mtile * 128 + t) * NCHUNK + nchunk;
        pbest[o] = b; pidx[o] = bi;
    }
}

// ---------------------------------------------------------------------------
// K2: reduce over the 8 N-chunks, write idx2d[p_r*134+p_c].
// p_r = er + 2*mr, p_c = ec + 2*mc. Chunks are ascending-n => strict > keeps
// the first (lowest) index on ties, matching argmin semantics.
// ---------------------------------------------------------------------------
__global__ __launch_bounds__(256) void reduce_kernel(const float* __restrict__ pbest,
                                                     const int* __restrict__ pidx,
                                                     int* __restrict__ idx2d) {
    const int gid = blockIdx.x * 256 + threadIdx.x;
    if (gid >= 4 * MCLS) return;
    const int cls = gid / MCLS, m = gid - cls * MCLS;
    const int mr = m / 67, mc = m - mr * 67;
    const int er = cls >> 1, ec = cls & 1;
    const float* pb = pbest + (cls * MPAD + m) * NCHUNK;
    const int* pi = pidx + (cls * MPAD + m) * NCHUNK;
    float b = pb[0]; int bi = pi[0];
    for (int c = 1; c < NCHUNK; ++c) {
        const float s = pb[c];
        if (s > b) { b = s; bi = pi[c]; }
    }
    const int pr = er + 2 * mr, pc = ec + 2 * mc;
    idx2d[pr * L1D + pc] = bi;
}

// ---------------------------------------------------------------------------
// K3: fold (overlap-add) sampled only at the 4096 output pixels.
// out_raw[oi][oj] = sum_{a,b} mem[idx2d[10+2oi-a][10+2oj-b]][a*15+b] (bounds-checked)
// ---------------------------------------------------------------------------
__global__ __launch_bounds__(256) void fold_kernel(const float* __restrict__ mem,
                                                   const int* __restrict__ idx2d,
                                                   float* __restrict__ outraw) {
    const int t = blockIdx.x * 256 + threadIdx.x;
    if (t >= 4096) return;
    const int oi = t >> 6, oj = t & 63;
    float s = 0.f;
    for (int a = 0; a < 15; ++a) {
        const int r = 10 + 2 * oi - a;
        if ((unsigned)r >= (unsigned)L1D) continue;
        for (int b = 0; b < 15; ++b) {
            const int c = 10 + 2 * oj - b;
            if ((unsigned)c >= (unsigned)L1D) continue;
            const int n = idx2d[r * L1D + c];
            s += mem[n * MDIM + a * 15 + b];
        }
    }
    outraw[t] = s;
}

// ---------------------------------------------------------------------------
// K4: divide by global max (single block).
// ---------------------------------------------------------------------------
__global__ __launch_bounds__(256) void norm_kernel(const float* __restrict__ outraw,
                                                   float* __restrict__ out) {
    __shared__ float red[256];
    const int t = threadIdx.x;
    float m = -3.0e38f;
    #pragma unroll
    for (int i = 0; i < 16; ++i) m = fmaxf(m, outraw[t + i * 256]);
    red[t] = m;
    __syncthreads();
    for (int s = 128; s > 0; s >>= 1) {
        if (t < s) red[t] = fmaxf(red[t], red[t + s]);
        __syncthreads();
    }
    const float mx = red[0];
    #pragma unroll
    for (int i = 0; i < 16; ++i) out[t + i * 256] = outraw[t + i * 256] / mx;
}

extern "C" void kernel_launch(void* const* d_in, const int* in_sizes, int n_in,
                              void* d_out, int out_size, void* d_ws, size_t ws_size,
                              hipStream_t stream) {
    const float* img = (const float*)d_in[0];   // 64*64 fp32
    const float* mem = (const float*)d_in[1];   // 16384*225 fp32
    float* out = (float*)d_out;                 // 4096 fp32

    float* ws = (float*)d_ws;
    float* cm = ws;                                   // 4*64*16384 = 4194304 f
    float* hn = cm + 4 * 64 * NMEM;                   // 16384 f
    float* pbest = hn + NMEM;                         // 4*4608*8 = 147456 f
    int* pidx = (int*)(pbest + 4 * MPAD * NCHUNK);    // 147456 i
    int* idx2d = pidx + 4 * MPAD * NCHUNK;            // 17956 i
    float* outraw = (float*)(idx2d + NPOS);           // 4096 f
    // total ~18.1 MB of ws

    prep_kernel<<<NMEM / 64, 64, 0, stream>>>(mem, cm, hn);
    gemm_argmin_kernel<<<dim3(36, NCHUNK, 4), 256, 0, stream>>>(img, cm, hn, pbest, pidx);
    reduce_kernel<<<(4 * MCLS + 255) / 256, 256, 0, stream>>>(pbest, pidx, idx2d);
    fold_kernel<<<16, 256, 0, stream>>>(mem, idx2d, outraw);
    norm_kernel<<<1, 256, 0, stream>>>(outraw, out);
}

// Round 2
// 596.447 us; speedup vs baseline: 1.1639x; 1.1639x over previous
//
#include <hip/hip_runtime.h>

#define NMEM 16384
#define MDIM 225
#define L1D 134
#define MCLS 4489    // 67*67
#define MPAD 4608    // 36*128
#define NCHUNK 8
#define CHUNK 2048
#define NSUB 64      // 32-col subtiles per chunk

typedef __attribute__((ext_vector_type(8))) short bf16x8;
typedef __attribute__((ext_vector_type(16))) float f32x16;

__device__ inline unsigned short f2bf(float f) {
    unsigned u = __float_as_uint(f);
    return (unsigned short)((u + 0x7FFFu + ((u >> 16) & 1u)) >> 16);
}
__device__ inline float bf2f(unsigned short h) {
    return __uint_as_float(((unsigned)h) << 16);
}

// ---------------------------------------------------------------------------
// K0: collapse 15x15 filters to parity-dependent 8x8; emit bf16 hi/lo split
// in n-major layout cmh/cml[cls][n][k] (k contiguous, 64 per row) + hn.
// ---------------------------------------------------------------------------
__global__ __launch_bounds__(64) void prep_kernel(const float* __restrict__ mem,
                                                  unsigned short* __restrict__ cmh,
                                                  unsigned short* __restrict__ cml,
                                                  float* __restrict__ hn) {
    __shared__ float lds[64 * 65];
    const int t = threadIdx.x;
    const int n = blockIdx.x * 64 + t;
    float* row = lds + t * 65;
    const float* mrow = mem + n * MDIM;
    float nrm = 0.f;
    for (int c = 0; c < 4; ++c) {
        const int er = c >> 1, ec = c & 1;
        #pragma unroll
        for (int k = 0; k < 64; ++k) row[k] = 0.f;
        for (int i = 0; i < 15; ++i) {
            const int u = (i + er) >> 1;
            for (int j = 0; j < 15; ++j) {
                const int v = (j + ec) >> 1;
                const float val = mrow[i * 15 + j];
                row[u * 8 + v] += val;
                if (c == 0) nrm += val * val;
            }
        }
        unsigned short* ph = cmh + ((size_t)(c * NMEM + n)) * 64;
        unsigned short* pl = cml + ((size_t)(c * NMEM + n)) * 64;
        #pragma unroll
        for (int k8 = 0; k8 < 8; ++k8) {
            bf16x8 h, l;
            #pragma unroll
            for (int j = 0; j < 8; ++j) {
                const float f = row[k8 * 8 + j];
                const unsigned short hb = f2bf(f);
                h[j] = (short)hb;
                l[j] = (short)f2bf(f - bf2f(hb));
            }
            *(bf16x8*)(ph + k8 * 8) = h;
            *(bf16x8*)(pl + k8 * 8) = l;
        }
    }
    hn[n] = 0.5f * nrm;
}

// ---------------------------------------------------------------------------
// K1: MFMA scoring. Grid (36 mtiles, 8 chunks, 4 cls), 256 thr = 4 waves.
// Wave w owns rows w*32..w*32+31 of the 128-row tile; K=64 A-frags (hi/lo)
// live in registers for the whole kernel. Per 32-col subtile: 12x
// v_mfma_f32_32x32x16_bf16 (3-product split), then per-lane running argmax
// (each lane owns one col-residue x 16 rows). Block epilogue -> top-4 per
// (row, chunk) candidates for the exact-rescue pass.
// A-frag: m=lane&31, k=(lane>>5)*8+j.  B-frag: n=lane&31, k=(lane>>5)*8+j.
// C/D: col=lane&31, row=(r&3)+8*(r>>2)+4*(lane>>5)  [HW-verified layout].
// ---------------------------------------------------------------------------
__global__ __launch_bounds__(256) void mfma_argmin_kernel(const float* __restrict__ img,
                                                          const unsigned short* __restrict__ cmh,
                                                          const unsigned short* __restrict__ cml,
                                                          const float* __restrict__ hn,
                                                          float* __restrict__ pcv,
                                                          int* __restrict__ pcn) {
    __shared__ float lds[8704];   // X tile 128x68 fp32; later reused as 2x 128x33
    const int mtile = blockIdx.x, chunk = blockIdx.y, cls = blockIdx.z;
    const int t = threadIdx.x;

    // Stage X tile (128 rows x 64 k, stride 68 for 16B-aligned frag reads).
    for (int e = t; e < 128 * 64; e += 256) {
        const int m = e >> 6, k = e & 63;
        const int mg = mtile * 128 + m;
        float v = 0.f;
        if (mg < MCLS) {
            const int mr = mg / 67, mc = mg - mr * 67;
            const int r = mr - 5 + (k >> 3), c2 = mc - 5 + (k & 7);
            if ((unsigned)r < 64u && (unsigned)c2 < 64u) v = img[r * 64 + c2];
        }
        lds[m * 68 + k] = v;
    }
    __syncthreads();

    const int wave = t >> 6, lane = t & 63;
    const int col = lane & 31, g = lane >> 5;
    const int arow = wave * 32 + (lane & 31);

    bf16x8 ah[4], al[4];
    #pragma unroll
    for (int s = 0; s < 4; ++s) {
        const float* xp = lds + arow * 68 + s * 16 + g * 8;
        #pragma unroll
        for (int j = 0; j < 8; ++j) {
            const float f = xp[j];
            const unsigned short hb = f2bf(f);
            ah[s][j] = (short)hb;
            al[s][j] = (short)f2bf(f - bf2f(hb));
        }
    }
    __syncthreads();   // all X reads done; lds reusable after this point

    const int nbase0 = chunk * CHUNK;
    const unsigned short* pbh = cmh + ((size_t)(cls * NMEM + nbase0 + col)) * 64 + g * 8;
    const unsigned short* pbl = cml + ((size_t)(cls * NMEM + nbase0 + col)) * 64 + g * 8;
    const float* ph = hn + nbase0 + col;

    float best[16];
    int bst[16];
    #pragma unroll
    for (int r = 0; r < 16; ++r) { best[r] = -3.0e38f; bst[r] = 0; }

    for (int st = 0; st < NSUB; ++st) {
        const unsigned short* bhp = pbh + st * 2048;   // 32 rows * 64 shorts
        const unsigned short* blp = pbl + st * 2048;
        const float hv = ph[st * 32];
        f32x16 acc = {0.f,0.f,0.f,0.f,0.f,0.f,0.f,0.f,0.f,0.f,0.f,0.f,0.f,0.f,0.f,0.f};
        #pragma unroll
        for (int s = 0; s < 4; ++s) {
            const bf16x8 bh = *(const bf16x8*)(bhp + s * 16);
            const bf16x8 bl = *(const bf16x8*)(blp + s * 16);
            acc = __builtin_amdgcn_mfma_f32_32x32x16_bf16(ah[s], bh, acc, 0, 0, 0);
            acc = __builtin_amdgcn_mfma_f32_32x32x16_bf16(al[s], bh, acc, 0, 0, 0);
            acc = __builtin_amdgcn_mfma_f32_32x32x16_bf16(ah[s], bl, acc, 0, 0, 0);
        }
        #pragma unroll
        for (int r = 0; r < 16; ++r) {
            const float s = acc[r] - hv;
            if (s > best[r]) { best[r] = s; bst[r] = st; }
        }
    }

    // Per-block: reduce 32 col-residue candidates -> top-4 per (row, chunk).
    float* lv = lds;                       // [128][33]
    int* li = (int*)(lds + 128 * 33);      // [128][33]
    #pragma unroll
    for (int r = 0; r < 16; ++r) {
        const int rloc = (r & 3) + 8 * (r >> 2) + 4 * g;
        lv[(wave * 32 + rloc) * 33 + col] = best[r];
        li[(wave * 32 + rloc) * 33 + col] = bst[r];
    }
    __syncthreads();
    if (t < 128) {
        float v4[4] = {-3.0e38f, -3.0e38f, -3.0e38f, -3.0e38f};
        int n4[4] = {0, 0, 0, 0};
        for (int j = 0; j < 32; ++j) {
            const float v = lv[t * 33 + j];
            const int n = nbase0 + li[t * 33 + j] * 32 + j;
            if (v > v4[3]) {
                if (v > v4[1]) {
                    if (v > v4[0]) {
                        v4[3]=v4[2]; n4[3]=n4[2]; v4[2]=v4[1]; n4[2]=n4[1];
                        v4[1]=v4[0]; n4[1]=n4[0]; v4[0]=v; n4[0]=n;
                    } else {
                        v4[3]=v4[2]; n4[3]=n4[2]; v4[2]=v4[1]; n4[2]=n4[1];
                        v4[1]=v; n4[1]=n;
                    }
                } else {
                    if (v > v4[2]) { v4[3]=v4[2]; n4[3]=n4[2]; v4[2]=v; n4[2]=n; }
                    else { v4[3]=v; n4[3]=n; }
                }
            }
        }
        const int o = ((cls * MPAD + mtile * 128 + t) * NCHUNK + chunk) * 4;
        #pragma unroll
        for (int j = 0; j < 4; ++j) { pcv[o + j] = v4[j]; pcn[o + j] = n4[j]; }
    }
}

// ---------------------------------------------------------------------------
// K2: exact rescue. Per position: among 32 candidates, re-score in exact fp32
// (directly from mem, only those within margin of the approx max), pick true
// argmax with lowest-index tie rule, write idx2d.
// ---------------------------------------------------------------------------
template<int ER, int EC>
__device__ float exact_score(const float* __restrict__ mrow, const float* __restrict__ x) {
    float s = 0.f;
    #pragma unroll
    for (int i = 0; i < 15; ++i) {
        const int u = (i + ER) >> 1;
        #pragma unroll
        for (int j = 0; j < 15; ++j) {
            const int v = (j + EC) >> 1;
            s = fmaf(mrow[i * 15 + j], x[u * 8 + v], s);
        }
    }
    return s;
}

__global__ __launch_bounds__(256) void rescue_kernel(const float* __restrict__ img,
                                                     const float* __restrict__ mem,
                                                     const float* __restrict__ hn,
                                                     const float* __restrict__ pcv,
                                                     const int* __restrict__ pcn,
                                                     int* __restrict__ idx2d) {
    const int gid = blockIdx.x * 256 + threadIdx.x;
    if (gid >= 4 * MCLS) return;
    const int cls = gid / MCLS, m = gid - cls * MCLS;
    const int mr = m / 67, mc = m - mr * 67;

    float x[64];
    #pragma unroll
    for (int u = 0; u < 8; ++u)
        #pragma unroll
        for (int v = 0; v < 8; ++v) {
            const int r = mr - 5 + u, c = mc - 5 + v;
            x[u * 8 + v] = ((unsigned)r < 64u && (unsigned)c < 64u) ? img[r * 64 + c] : 0.f;
        }

    const int o = (cls * MPAD + m) * NCHUNK * 4;
    float vmax = -3.0e38f;
    for (int i = 0; i < 32; ++i) vmax = fmaxf(vmax, pcv[o + i]);
    const float thr = vmax - 0.15f;

    float best = -3.0e38f; int bn = 0x7FFFFFFF;
    for (int i = 0; i < 32; ++i) {
        if (pcv[o + i] < thr) continue;
        const int n = pcn[o + i];
        const float* mrow = mem + (size_t)n * MDIM;
        float s;
        if (cls == 0)      s = exact_score<0, 0>(mrow, x);
        else if (cls == 1) s = exact_score<0, 1>(mrow, x);
        else if (cls == 2) s = exact_score<1, 0>(mrow, x);
        else               s = exact_score<1, 1>(mrow, x);
        s -= hn[n];
        if (s > best || (s == best && n < bn)) { best = s; bn = n; }
    }
    const int er = cls >> 1, ec = cls & 1;
    idx2d[(er + 2 * mr) * L1D + (ec + 2 * mc)] = bn;
}

// ---------------------------------------------------------------------------
// K3: fold (overlap-add) sampled only at the 4096 output pixels.
// ---------------------------------------------------------------------------
__global__ __launch_bounds__(256) void fold_kernel(const float* __restrict__ mem,
                                                   const int* __restrict__ idx2d,
                                                   float* __restrict__ outraw) {
    const int t = blockIdx.x * 256 + threadIdx.x;
    if (t >= 4096) return;
    const int oi = t >> 6, oj = t & 63;
    float s = 0.f;
    for (int a = 0; a < 15; ++a) {
        const int r = 10 + 2 * oi - a;
        if ((unsigned)r >= (unsigned)L1D) continue;
        for (int b = 0; b < 15; ++b) {
            const int c = 10 + 2 * oj - b;
            if ((unsigned)c >= (unsigned)L1D) continue;
            const int n = idx2d[r * L1D + c];
            s += mem[(size_t)n * MDIM + a * 15 + b];
        }
    }
    outraw[t] = s;
}

// ---------------------------------------------------------------------------
// K4: divide by global max (single block).
// ---------------------------------------------------------------------------
__global__ __launch_bounds__(256) void norm_kernel(const float* __restrict__ outraw,
                                                   float* __restrict__ out) {
    __shared__ float red[256];
    const int t = threadIdx.x;
    float m = -3.0e38f;
    #pragma unroll
    for (int i = 0; i < 16; ++i) m = fmaxf(m, outraw[t + i * 256]);
    red[t] = m;
    __syncthreads();
    for (int s = 128; s > 0; s >>= 1) {
        if (t < s) red[t] = fmaxf(red[t], red[t + s]);
        __syncthreads();
    }
    const float mx = red[0];
    #pragma unroll
    for (int i = 0; i < 16; ++i) out[t + i * 256] = outraw[t + i * 256] / mx;
}

extern "C" void kernel_launch(void* const* d_in, const int* in_sizes, int n_in,
                              void* d_out, int out_size, void* d_ws, size_t ws_size,
                              hipStream_t stream) {
    const float* img = (const float*)d_in[0];   // 64*64 fp32
    const float* mem = (const float*)d_in[1];   // 16384*225 fp32
    float* out = (float*)d_out;                 // 4096 fp32

    unsigned short* cmh = (unsigned short*)d_ws;          // 4*16384*64 bf16 (8.39 MB)
    unsigned short* cml = cmh + (size_t)4 * NMEM * 64;    // 8.39 MB
    float* hn = (float*)(cml + (size_t)4 * NMEM * 64);    // 64 KB
    float* pcv = hn + NMEM;                               // 4*4608*8*4 = 2.36 MB
    int* pcn = (int*)(pcv + (size_t)4 * MPAD * NCHUNK * 4);  // 2.36 MB
    int* idx2d = pcn + (size_t)4 * MPAD * NCHUNK * 4;     // 72 KB
    float* outraw = (float*)(idx2d + L1D * L1D);          // 16 KB
    // total ~21.6 MB of ws

    prep_kernel<<<NMEM / 64, 64, 0, stream>>>(mem, cmh, cml, hn);
    mfma_argmin_kernel<<<dim3(36, NCHUNK, 4), 256, 0, stream>>>(img, cmh, cml, hn, pcv, pcn);
    rescue_kernel<<<(4 * MCLS + 255) / 256, 256, 0, stream>>>(img, mem, hn, pcv, pcn, idx2d);
    fold_kernel<<<16, 256, 0, stream>>>(mem, idx2d, outraw);
    norm_kernel<<<1, 256, 0, stream>>>(outraw, out);
}